// Round 1
// baseline (733.470 us; speedup 1.0000x reference)
//
#include <hip/hip_runtime.h>
#include <math.h>

#define D 64
#define K 4096
#define NCHUNK 4
#define KC (K / NCHUNK)

// ---------------------------------------------------------------------------
// e_sq[k] = sum_d emb[k][d]^2
// ---------------------------------------------------------------------------
__global__ __launch_bounds__(256) void esq_kernel(const float* __restrict__ emb,
                                                  float* __restrict__ e_sq) {
  int k = blockIdx.x * 256 + threadIdx.x;
  if (k >= K) return;
  const float* e = emb + (size_t)k * D;
  float s = 0.f;
#pragma unroll
  for (int d = 0; d < D; ++d) s = fmaf(e[d], e[d], s);
  e_sq[k] = s;
}

// ---------------------------------------------------------------------------
// Per-row argmin over one K-chunk. One thread = one row. Code data (emb,
// e_sq) is wave-uniform -> scalar loads; z stays in 64 VGPRs.
// d2 = (zsq - 2*dot) + e_sq[k], matching the reference's association.
// Strict '<' with ascending k => first-occurrence argmin like jnp.argmin.
// ---------------------------------------------------------------------------
__global__ __launch_bounds__(256) void dist_kernel(const float* __restrict__ z_e,
                                                   const float* __restrict__ emb,
                                                   const float* __restrict__ e_sq,
                                                   float* __restrict__ pmin,
                                                   int* __restrict__ pidx) {
  const int row = blockIdx.x * 256 + threadIdx.x;
  const int chunk = blockIdx.y;
  const int k0 = chunk * KC;

  float z[D];
  const float4* zp = (const float4*)(z_e + (size_t)row * D);
#pragma unroll
  for (int i = 0; i < D / 4; ++i) {
    float4 v = zp[i];
    z[4 * i + 0] = v.x;
    z[4 * i + 1] = v.y;
    z[4 * i + 2] = v.z;
    z[4 * i + 3] = v.w;
  }
  float zsq = 0.f;
#pragma unroll
  for (int d = 0; d < D; ++d) zsq = fmaf(z[d], z[d], zsq);

  float best = __builtin_inff();
  int bidx = k0;

  for (int k = k0; k < k0 + KC; k += 4) {
    const float* e0 = emb + (size_t)k * D;
    float d0 = 0.f, d1 = 0.f, d2 = 0.f, d3 = 0.f;
#pragma unroll
    for (int d = 0; d < D; ++d) {
      float zd = z[d];
      d0 = fmaf(e0[d], zd, d0);
      d1 = fmaf(e0[D + d], zd, d1);
      d2 = fmaf(e0[2 * D + d], zd, d2);
      d3 = fmaf(e0[3 * D + d], zd, d3);
    }
    float q0 = (zsq - 2.f * d0) + e_sq[k + 0];
    float q1 = (zsq - 2.f * d1) + e_sq[k + 1];
    float q2 = (zsq - 2.f * d2) + e_sq[k + 2];
    float q3 = (zsq - 2.f * d3) + e_sq[k + 3];
    if (q0 < best) { best = q0; bidx = k; }
    if (q1 < best) { best = q1; bidx = k + 1; }
    if (q2 < best) { best = q2; bidx = k + 2; }
    if (q3 < best) { best = q3; bidx = k + 3; }
  }
  pmin[(size_t)row * NCHUNK + chunk] = best;
  pidx[(size_t)row * NCHUNK + chunk] = bidx;
}

// ---------------------------------------------------------------------------
// Combine chunk argmins, gather z_q, write z_q_st + indices, accumulate
// per-block loss partials and code-usage histogram. One 64-lane wave per row.
// ---------------------------------------------------------------------------
__global__ __launch_bounds__(256) void combine_kernel(const float* __restrict__ z_e,
                                                      const float* __restrict__ emb,
                                                      const float* __restrict__ pmin,
                                                      const int* __restrict__ pidx,
                                                      float* __restrict__ out_zq,
                                                      float* __restrict__ out_idx,
                                                      int* __restrict__ counts,
                                                      float* __restrict__ block_loss) {
  const int tid = threadIdx.x;
  const int wave = tid >> 6;
  const int lane = tid & 63;
  const int row = blockIdx.x * 4 + wave;

  // chunks ascending, strict '<' => global first-occurrence argmin
  float best = pmin[(size_t)row * NCHUNK + 0];
  int bidx = pidx[(size_t)row * NCHUNK + 0];
#pragma unroll
  for (int c = 1; c < NCHUNK; ++c) {
    float m = pmin[(size_t)row * NCHUNK + c];
    int ix = pidx[(size_t)row * NCHUNK + c];
    if (m < best) { best = m; bidx = ix; }
  }

  float ze = z_e[(size_t)row * D + lane];
  float zq = emb[(size_t)bidx * D + lane];
  float st = ze + (zq - ze);  // straight-through, same formula as reference
  out_zq[(size_t)row * D + lane] = st;

  float diff = zq - ze;
  float sq = diff * diff;
#pragma unroll
  for (int off = 32; off > 0; off >>= 1) sq += __shfl_down(sq, off);

  __shared__ float ls[4];
  if (lane == 0) {
    ls[wave] = sq;
    out_idx[row] = (float)bidx;
    atomicAdd(&counts[bidx], 1);
  }
  __syncthreads();
  if (tid == 0) block_loss[blockIdx.x] = ls[0] + ls[1] + ls[2] + ls[3];
}

// ---------------------------------------------------------------------------
// Final scalars: commitment loss, perplexity, n_active. Single block.
// ---------------------------------------------------------------------------
__global__ __launch_bounds__(1024) void stats_kernel(const float* __restrict__ block_loss,
                                                     int nblocks,
                                                     const int* __restrict__ counts,
                                                     float* __restrict__ out_scalars,
                                                     int N) {
  const int tid = threadIdx.x;
  const int wave = tid >> 6;
  const int lane = tid & 63;

  float lsum = 0.f;
  for (int i = tid; i < nblocks; i += 1024) lsum += block_loss[i];

  float ent = 0.f;
  int act = 0;
  const float invN = 1.0f / (float)N;
  for (int k = tid; k < K; k += 1024) {
    float p = (float)counts[k] * invN;
    ent += p * logf(p + 1e-10f);
    act += (p > 0.001f) ? 1 : 0;
  }

#pragma unroll
  for (int off = 32; off > 0; off >>= 1) {
    lsum += __shfl_down(lsum, off);
    ent += __shfl_down(ent, off);
    act += __shfl_down(act, off);
  }

  __shared__ float sl[16], se[16];
  __shared__ int sa[16];
  if (lane == 0) { sl[wave] = lsum; se[wave] = ent; sa[wave] = act; }
  __syncthreads();
  if (tid == 0) {
    float L = 0.f, E = 0.f;
    int A = 0;
#pragma unroll
    for (int w = 0; w < 16; ++w) { L += sl[w]; E += se[w]; A += sa[w]; }
    out_scalars[0] = 0.25f * L / ((float)N * (float)D);  // commitment loss
    out_scalars[1] = expf(-E);                            // perplexity
    out_scalars[2] = (float)A;                            // n_active
  }
}

extern "C" void kernel_launch(void* const* d_in, const int* in_sizes, int n_in,
                              void* d_out, int out_size, void* d_ws, size_t ws_size,
                              hipStream_t stream) {
  const float* z_e = (const float*)d_in[0];
  const float* emb = (const float*)d_in[1];
  const int N = in_sizes[0] / D;  // 65536

  float* out = (float*)d_out;
  float* out_zq = out;
  float* out_idx = out + (size_t)N * D;
  float* out_scalars = out + (size_t)N * (D + 1);

  char* ws = (char*)d_ws;
  int* counts = (int*)ws;                                        // 16 KB
  float* e_sq = (float*)(ws + 16384);                            // 16 KB
  float* pmin = (float*)(ws + 32768);                            // N*4*4 B
  int* pidx = (int*)(ws + 32768 + (size_t)N * NCHUNK * 4);       // N*4*4 B
  float* block_loss =
      (float*)(ws + 32768 + 2 * (size_t)N * NCHUNK * 4);         // (N/4)*4 B

  hipMemsetAsync(counts, 0, K * sizeof(int), stream);

  esq_kernel<<<K / 256, 256, 0, stream>>>(emb, e_sq);
  dist_kernel<<<dim3(N / 256, NCHUNK), 256, 0, stream>>>(z_e, emb, e_sq, pmin, pidx);
  combine_kernel<<<N / 4, 256, 0, stream>>>(z_e, emb, pmin, pidx, out_zq, out_idx,
                                            counts, block_loss);
  stats_kernel<<<1, 1024, 0, stream>>>(block_loss, N / 4, counts, out_scalars, N);
}

// Round 2
// 596.554 us; speedup vs baseline: 1.2295x; 1.2295x over previous
//
#include <hip/hip_runtime.h>
#include <math.h>

#define D 64
#define K 4096
#define NCHUNK 4
#define KC (K / NCHUNK)

typedef float f32x2 __attribute__((ext_vector_type(2)));

// ---------------------------------------------------------------------------
// e_sq[k] = sum_d emb[k][d]^2
// ---------------------------------------------------------------------------
__global__ __launch_bounds__(256) void esq_kernel(const float* __restrict__ emb,
                                                  float* __restrict__ e_sq) {
  int k = blockIdx.x * 256 + threadIdx.x;
  if (k >= K) return;
  const float* e = emb + (size_t)k * D;
  float s = 0.f;
#pragma unroll
  for (int d = 0; d < D; ++d) s = fmaf(e[d], e[d], s);
  e_sq[k] = s;
}

// ---------------------------------------------------------------------------
// Per-row argmin over one K-chunk. One thread = one row.
// __launch_bounds__(256,4): VGPR cap 128 so z[] (64 floats = 32 f32x2) stays
// resident in VGPRs -- round 1's cap of 36 VGPRs caused a 16.6 GB z refetch.
// Embedding operands are wave-uniform -> scalar loads (SGPR operand on the
// v_pk_fma_f32). float2 chains -> v_pk_fma_f32 (VOP3P packed fp32).
// Strict '<' ascending k => first-occurrence argmin like jnp.argmin.
// ---------------------------------------------------------------------------
__global__ __launch_bounds__(256, 4) void dist_kernel(const float* __restrict__ z_e,
                                                      const float* __restrict__ emb,
                                                      const float* __restrict__ e_sq,
                                                      float* __restrict__ pmin,
                                                      int* __restrict__ pidx) {
  const int row = blockIdx.x * 256 + threadIdx.x;
  const int chunk = blockIdx.y;
  const int k0 = chunk * KC;

  f32x2 z[D / 2];
  const f32x2* zp = (const f32x2*)(z_e + (size_t)row * D);
#pragma unroll
  for (int i = 0; i < D / 2; ++i) z[i] = zp[i];

  f32x2 zs = {0.f, 0.f};
#pragma unroll
  for (int i = 0; i < D / 2; ++i) zs = __builtin_elementwise_fma(z[i], z[i], zs);
  const float zsq = zs.x + zs.y;

  float best = __builtin_inff();
  int bidx = k0;

  for (int k = k0; k < k0 + KC; k += 4) {
    const f32x2* e0 = (const f32x2*)(emb + (size_t)k * D);
    f32x2 a0 = {0.f, 0.f}, a1 = {0.f, 0.f}, a2 = {0.f, 0.f}, a3 = {0.f, 0.f};
#pragma unroll
    for (int i = 0; i < D / 2; ++i) {
      f32x2 zi = z[i];
      a0 = __builtin_elementwise_fma(e0[i], zi, a0);
      a1 = __builtin_elementwise_fma(e0[D / 2 + i], zi, a1);
      a2 = __builtin_elementwise_fma(e0[D + i], zi, a2);
      a3 = __builtin_elementwise_fma(e0[3 * D / 2 + i], zi, a3);
    }
    float q0 = (zsq - 2.f * (a0.x + a0.y)) + e_sq[k + 0];
    float q1 = (zsq - 2.f * (a1.x + a1.y)) + e_sq[k + 1];
    float q2 = (zsq - 2.f * (a2.x + a2.y)) + e_sq[k + 2];
    float q3 = (zsq - 2.f * (a3.x + a3.y)) + e_sq[k + 3];
    if (q0 < best) { best = q0; bidx = k; }
    if (q1 < best) { best = q1; bidx = k + 1; }
    if (q2 < best) { best = q2; bidx = k + 2; }
    if (q3 < best) { best = q3; bidx = k + 3; }
  }
  pmin[(size_t)row * NCHUNK + chunk] = best;
  pidx[(size_t)row * NCHUNK + chunk] = bidx;
}

// ---------------------------------------------------------------------------
// Combine chunk argmins, gather z_q, write z_q_st + indices, accumulate
// per-block loss partials and code-usage histogram. One 64-lane wave per row.
// ---------------------------------------------------------------------------
__global__ __launch_bounds__(256) void combine_kernel(const float* __restrict__ z_e,
                                                      const float* __restrict__ emb,
                                                      const float* __restrict__ pmin,
                                                      const int* __restrict__ pidx,
                                                      float* __restrict__ out_zq,
                                                      float* __restrict__ out_idx,
                                                      int* __restrict__ counts,
                                                      float* __restrict__ block_loss) {
  const int tid = threadIdx.x;
  const int wave = tid >> 6;
  const int lane = tid & 63;
  const int row = blockIdx.x * 4 + wave;

  // chunks ascending, strict '<' => global first-occurrence argmin
  float best = pmin[(size_t)row * NCHUNK + 0];
  int bidx = pidx[(size_t)row * NCHUNK + 0];
#pragma unroll
  for (int c = 1; c < NCHUNK; ++c) {
    float m = pmin[(size_t)row * NCHUNK + c];
    int ix = pidx[(size_t)row * NCHUNK + c];
    if (m < best) { best = m; bidx = ix; }
  }

  float ze = z_e[(size_t)row * D + lane];
  float zq = emb[(size_t)bidx * D + lane];
  float st = ze + (zq - ze);  // straight-through, same formula as reference
  out_zq[(size_t)row * D + lane] = st;

  float diff = zq - ze;
  float sq = diff * diff;
#pragma unroll
  for (int off = 32; off > 0; off >>= 1) sq += __shfl_down(sq, off);

  __shared__ float ls[4];
  if (lane == 0) {
    ls[wave] = sq;
    out_idx[row] = (float)bidx;
    atomicAdd(&counts[bidx], 1);
  }
  __syncthreads();
  if (tid == 0) block_loss[blockIdx.x] = ls[0] + ls[1] + ls[2] + ls[3];
}

// ---------------------------------------------------------------------------
// Final scalars: commitment loss, perplexity, n_active. Single block.
// ---------------------------------------------------------------------------
__global__ __launch_bounds__(1024) void stats_kernel(const float* __restrict__ block_loss,
                                                     int nblocks,
                                                     const int* __restrict__ counts,
                                                     float* __restrict__ out_scalars,
                                                     int N) {
  const int tid = threadIdx.x;
  const int wave = tid >> 6;
  const int lane = tid & 63;

  float lsum = 0.f;
  for (int i = tid; i < nblocks; i += 1024) lsum += block_loss[i];

  float ent = 0.f;
  int act = 0;
  const float invN = 1.0f / (float)N;
  for (int k = tid; k < K; k += 1024) {
    float p = (float)counts[k] * invN;
    ent += p * logf(p + 1e-10f);
    act += (p > 0.001f) ? 1 : 0;
  }

#pragma unroll
  for (int off = 32; off > 0; off >>= 1) {
    lsum += __shfl_down(lsum, off);
    ent += __shfl_down(ent, off);
    act += __shfl_down(act, off);
  }

  __shared__ float sl[16], se[16];
  __shared__ int sa[16];
  if (lane == 0) { sl[wave] = lsum; se[wave] = ent; sa[wave] = act; }
  __syncthreads();
  if (tid == 0) {
    float L = 0.f, E = 0.f;
    int A = 0;
#pragma unroll
    for (int w = 0; w < 16; ++w) { L += sl[w]; E += se[w]; A += sa[w]; }
    out_scalars[0] = 0.25f * L / ((float)N * (float)D);  // commitment loss
    out_scalars[1] = expf(-E);                            // perplexity
    out_scalars[2] = (float)A;                            // n_active
  }
}

extern "C" void kernel_launch(void* const* d_in, const int* in_sizes, int n_in,
                              void* d_out, int out_size, void* d_ws, size_t ws_size,
                              hipStream_t stream) {
  const float* z_e = (const float*)d_in[0];
  const float* emb = (const float*)d_in[1];
  const int N = in_sizes[0] / D;  // 65536

  float* out = (float*)d_out;
  float* out_zq = out;
  float* out_idx = out + (size_t)N * D;
  float* out_scalars = out + (size_t)N * (D + 1);

  char* ws = (char*)d_ws;
  int* counts = (int*)ws;                                        // 16 KB
  float* e_sq = (float*)(ws + 16384);                            // 16 KB
  float* pmin = (float*)(ws + 32768);                            // N*4*4 B
  int* pidx = (int*)(ws + 32768 + (size_t)N * NCHUNK * 4);       // N*4*4 B
  float* block_loss =
      (float*)(ws + 32768 + 2 * (size_t)N * NCHUNK * 4);         // (N/4)*4 B

  hipMemsetAsync(counts, 0, K * sizeof(int), stream);

  esq_kernel<<<K / 256, 256, 0, stream>>>(emb, e_sq);
  dist_kernel<<<dim3(N / 256, NCHUNK), 256, 0, stream>>>(z_e, emb, e_sq, pmin, pidx);
  combine_kernel<<<N / 4, 256, 0, stream>>>(z_e, emb, pmin, pidx, out_zq, out_idx,
                                            counts, block_loss);
  stats_kernel<<<1, 1024, 0, stream>>>(block_loss, N / 4, counts, out_scalars, N);
}